// Round 2
// baseline (204.610 us; speedup 1.0000x reference)
//
#include <hip/hip_runtime.h>

#define BB 2
#define TT 2048
#define DD 1024
#define HH 16
#define HD 64
#define MM (BB*TT)

typedef __bf16 bf16;
typedef __bf16 bf16x4 __attribute__((ext_vector_type(4)));
typedef __bf16 bf16x8 __attribute__((ext_vector_type(8)));
typedef float  f32x4  __attribute__((ext_vector_type(4)));

#define QSCALE 0.1803368801111244f   // 0.125 * log2(e)
#define M0 16.0f                     // fixed softmax shift (exp2 domain)

__device__ __forceinline__ void gl_lds16(const void* g, void* l) {
  __builtin_amdgcn_global_load_lds(
      (const __attribute__((address_space(1))) void*)g,
      (__attribute__((address_space(3))) void*)l, 16, 0, 0);
}
__device__ __forceinline__ f32x4 mfma16(bf16x8 a, bf16x8 b, f32x4 c) {
  return __builtin_amdgcn_mfma_f32_16x16x32_bf16(a, b, c, 0, 0, 0);
}

// ---------------------------------------------------------------------------
// single fused convert: x (4M elems) + 4 weights (1M each) fp32 -> bf16
// ---------------------------------------------------------------------------
__global__ void cvt_all(const float* __restrict__ x,
                        const float* __restrict__ w0, const float* __restrict__ w1,
                        const float* __restrict__ w2, const float* __restrict__ w3,
                        bf16* __restrict__ xd,
                        bf16* __restrict__ d0, bf16* __restrict__ d1,
                        bf16* __restrict__ d2, bf16* __restrict__ d3) {
  int i = blockIdx.x * blockDim.x + threadIdx.x;   // 2M float4 slots
  const float* s;
  bf16* d;
  int off;
  if (i < (1 << 20)) { s = x; d = xd; off = i; }
  else {
    int j = (i - (1 << 20)) >> 18;
    off = (i - (1 << 20)) & ((1 << 18) - 1);
    s = (j == 0) ? w0 : (j == 1) ? w1 : (j == 2) ? w2 : w3;
    d = (j == 0) ? d0 : (j == 1) ? d1 : (j == 2) ? d2 : d3;
  }
  float4 v = ((const float4*)s)[off];
  bf16x4 o = { (bf16)v.x, (bf16)v.y, (bf16)v.z, (bf16)v.w };
  ((bf16x4*)d)[off] = o;
}

// ---------------------------------------------------------------------------
// Fused QKV, 512 blocks x 512 threads (8 waves).
// R-polish 1 (resubmit after container flake): BK=64 + XOR-chunk swizzle
// (pre-swizzled global source, linear global_load_lds dest — same scheme as
// tile_core64). Old BK=32 linear layout was ~8-way conflicted:
// SQ_LDS_BANK_CONFLICT 4.2M/dispatch ≈ 15% of cycles.
//   j<8 : QK-fused block. Wave grid 2x4 (64 rows x 32 cols per wave):
//         8 ds_read_b128 per 16 MFMA (was 10/16), 16 K-steps (was 32) so
//         half the barrier/vmcnt(0) drains.
//   j>=8: V^T block, wave grid 4x2, same BK=64 swizzled core.
// LDS 48KB/block, target <=128 VGPR -> 2 blocks/CU, 16 waves/CU.
// ---------------------------------------------------------------------------
__launch_bounds__(512, 4)
__global__ void gemm_qkv(const bf16* __restrict__ X,
                         const bf16* __restrict__ Wq, const bf16* __restrict__ Wk,
                         const bf16* __restrict__ Wv,
                         const float* __restrict__ bq, const float* __restrict__ bk,
                         const float* __restrict__ bv,
                         bf16* __restrict__ qb, bf16* __restrict__ kb,
                         bf16* __restrict__ vtb,
                         float* __restrict__ kf, float* __restrict__ vf) {
  __shared__ bf16 sA [128 * 64];     // 16 KB
  __shared__ bf16 sB0[128 * 64];     // 16 KB
  __shared__ bf16 sB1[128 * 64];     // 16 KB (QK path only)
  const int tid  = threadIdx.x;
  const int wv   = tid >> 6;
  const int lane = tid & 63;
  const int quad = lane >> 4, l15 = lane & 15;
  const int g    = blockIdx.x >> 4;
  const int j    = blockIdx.x & 15;
  const int srow = tid >> 3;                 // 0..63: row within one stage pass
  const int schk = (tid & 7) ^ (srow & 7);   // swizzled SOURCE chunk
  const int rswz = l15 & 7;                  // matching read-side XOR
  char* lA  = (char*)sA  + wv * 1024;
  char* lB0 = (char*)sB0 + wv * 1024;
  char* lB1 = (char*)sB1 + wv * 1024;

  if (j < 8) {
    const int wy = wv >> 2, wx = wv & 3;     // 2x4 wave grid
    const int m0 = g * 128;                  // tokens
    const int n0 = j * 128;                  // output dim
    const bf16* Ab  = X  + (size_t)(m0 + srow) * DD + schk * 8;
    const bf16* Bqb = Wq + (size_t)(n0 + srow) * DD + schk * 8;
    const bf16* Bkb = Wk + (size_t)(n0 + srow) * DD + schk * 8;
    f32x4 accq[4][2] = {}, acck[4][2] = {};
    for (int k0 = 0; k0 < DD; k0 += 64) {
      gl_lds16(Ab  + k0,               lA);
      gl_lds16(Ab  + 64 * DD + k0,     lA  + 8192);
      gl_lds16(Bqb + k0,               lB0);
      gl_lds16(Bqb + 64 * DD + k0,     lB0 + 8192);
      gl_lds16(Bkb + k0,               lB1);
      gl_lds16(Bkb + 64 * DD + k0,     lB1 + 8192);
      __syncthreads();
#pragma unroll
      for (int h = 0; h < 2; h++) {
        bf16x8 af[4], bq_[2], bk_[2];
#pragma unroll
        for (int mi = 0; mi < 4; mi++)
          af[mi] = *(const bf16x8*)(sA + (wy * 64 + mi * 16 + l15) * 64
                                       + (((h * 4 + quad) ^ rswz) * 8));
#pragma unroll
        for (int ni = 0; ni < 2; ni++) {
          bq_[ni] = *(const bf16x8*)(sB0 + (wx * 32 + ni * 16 + l15) * 64
                                         + (((h * 4 + quad) ^ rswz) * 8));
          bk_[ni] = *(const bf16x8*)(sB1 + (wx * 32 + ni * 16 + l15) * 64
                                         + (((h * 4 + quad) ^ rswz) * 8));
        }
#pragma unroll
        for (int mi = 0; mi < 4; mi++)
#pragma unroll
          for (int ni = 0; ni < 2; ni++) {
            accq[mi][ni] = mfma16(af[mi], bq_[ni], accq[mi][ni]);
            acck[mi][ni] = mfma16(af[mi], bk_[ni], acck[mi][ni]);
          }
      }
      __syncthreads();
    }
    for (int mi = 0; mi < 4; mi++)
      for (int ni = 0; ni < 2; ni++)
        for (int r = 0; r < 4; r++) {
          int m = m0 + wy * 64 + mi * 16 + quad * 4 + r;
          int n = n0 + wx * 32 + ni * 16 + l15;
          int b = m >> 11, t = m & (TT - 1);
          int h = n >> 6,  d = n & (HD - 1);
          size_t idx = ((size_t)(b * HH + h) * TT + t) * HD + d;
          qb[idx] = (bf16)((accq[mi][ni][r] + bq[n]) * QSCALE);
          float vk = acck[mi][ni][r] + bk[n];
          kb[idx] = (bf16)vk;
          kf[idx] = vk;
        }
  } else {
    const int wy = wv >> 1, wx = wv & 1;     // 4x2 wave grid
    const int m0 = (j - 8) * 128;            // Wv rows (h*64+d)
    const int n0 = g * 128;                  // tokens
    const bf16* Ab = Wv + (size_t)(m0 + srow) * DD + schk * 8;
    const bf16* Bb = X  + (size_t)(n0 + srow) * DD + schk * 8;
    f32x4 acc[2][4] = {};
    for (int k0 = 0; k0 < DD; k0 += 64) {
      gl_lds16(Ab + k0,               lA);
      gl_lds16(Ab + 64 * DD + k0,     lA  + 8192);
      gl_lds16(Bb + k0,               lB0);
      gl_lds16(Bb + 64 * DD + k0,     lB0 + 8192);
      __syncthreads();
#pragma unroll
      for (int h = 0; h < 2; h++) {
        bf16x8 af[2], bx_[4];
#pragma unroll
        for (int mi = 0; mi < 2; mi++)
          af[mi] = *(const bf16x8*)(sA + (wy * 32 + mi * 16 + l15) * 64
                                       + (((h * 4 + quad) ^ rswz) * 8));
#pragma unroll
        for (int ni = 0; ni < 4; ni++)
          bx_[ni] = *(const bf16x8*)(sB0 + (wx * 64 + ni * 16 + l15) * 64
                                        + (((h * 4 + quad) ^ rswz) * 8));
#pragma unroll
        for (int mi = 0; mi < 2; mi++)
#pragma unroll
          for (int ni = 0; ni < 4; ni++)
            acc[mi][ni] = mfma16(af[mi], bx_[ni], acc[mi][ni]);
      }
      __syncthreads();
    }
    for (int mi = 0; mi < 2; mi++) {
      int mbase = m0 + wy * 32 + mi * 16 + quad * 4;
      float brv[4];
      for (int r = 0; r < 4; r++) brv[r] = bv[mbase + r];
      int h = mbase >> 6, dbase = mbase & (HD - 1);
      for (int ni = 0; ni < 4; ni++) {
        int tok = n0 + wx * 64 + ni * 16 + l15;
        int b = tok >> 11, t = tok & (TT - 1);
        int bh = b * HH + h;
        float4 vv;
        float* vp = &vv.x;
        for (int r = 0; r < 4; r++) {
          float v = acc[mi][ni][r] + brv[r];
          vp[r] = v;
          vtb[((size_t)bh * HD + dbase + r) * TT + t] = (bf16)v;
        }
        *(float4*)&vf[((size_t)bh * TT + t) * HD + dbase] = vv;
      }
    }
  }
}

// ---------------------------------------------------------------------------
// gemm_o tile core (BK=64, swizzled) — unchanged.
// ---------------------------------------------------------------------------
template<int BM, int BN>
__device__ __forceinline__ void tile_core64(const bf16* __restrict__ A,
                                            const bf16* __restrict__ W,
                                            int m0, int n0,
                                            bf16* sA, bf16* sB,
                                            f32x4 (&acc)[BM/32][BN/32]) {
  const int tid  = threadIdx.x;
  const int wv   = tid >> 6;
  const int l15  = tid & 15;
  const int quad = (tid & 63) >> 4;
  const int wy   = wv >> 1, wx = wv & 1;
  const int MI_  = BM / 32, NI_ = BN / 32;
  const int srow = tid >> 3;
  const int schk = (tid & 7) ^ (srow & 7);
  const int rswz = l15 & 7;
  const bf16* Ab = A + (size_t)(m0 + srow) * DD + schk * 8;
  const bf16* Wb = W + (size_t)(n0 + srow) * DD + schk * 8;
  char* lA = (char*)sA + wv * 1024;
  char* lB = (char*)sB + wv * 1024;
  for (int k0 = 0; k0 < DD; k0 += 64) {
#pragma unroll
    for (int j = 0; j < BM / 32; j++)
      gl_lds16(Ab + (size_t)j * 32 * DD + k0, lA + j * 4096);
#pragma unroll
    for (int j = 0; j < BN / 32; j++)
      gl_lds16(Wb + (size_t)j * 32 * DD + k0, lB + j * 4096);
    __syncthreads();
#pragma unroll
    for (int h = 0; h < 2; h++) {
      bf16x8 af[MI_], bw[NI_];
#pragma unroll
      for (int mi = 0; mi < MI_; mi++)
        af[mi] = *(const bf16x8*)(sA + (wy * (BM / 2) + mi * 16 + l15) * 64
                                     + (((h * 4 + quad) ^ rswz) * 8));
#pragma unroll
      for (int ni = 0; ni < NI_; ni++)
        bw[ni] = *(const bf16x8*)(sB + (wx * (BN / 2) + ni * 16 + l15) * 64
                                     + (((h * 4 + quad) ^ rswz) * 8));
#pragma unroll
      for (int mi = 0; mi < MI_; mi++)
#pragma unroll
        for (int ni = 0; ni < NI_; ni++)
          acc[mi][ni] = mfma16(af[mi], bw[ni], acc[mi][ni]);
    }
    __syncthreads();
  }
}

__launch_bounds__(256)
__global__ void gemm_o(const bf16* __restrict__ A, const bf16* __restrict__ W,
                       const float* __restrict__ bias, float* __restrict__ out) {
  __shared__ bf16 sA[64 * 64];
  __shared__ bf16 sB[128 * 64];
  const int m0 = blockIdx.x * 64;
  const int n0 = blockIdx.y * 128;
  f32x4 acc[2][4] = {};
  tile_core64<64, 128>(A, W, m0, n0, sA, sB, acc);
  const int wv = threadIdx.x >> 6;
  const int l15 = threadIdx.x & 15, quad = (threadIdx.x & 63) >> 4;
  const int wy = wv >> 1, wx = wv & 1;
  for (int mi = 0; mi < 2; mi++)
    for (int ni = 0; ni < 4; ni++)
      for (int r = 0; r < 4; r++) {
        int m = m0 + wy * 32 + mi * 16 + quad * 4 + r;
        int n = n0 + wx * 64 + ni * 16 + l15;
        out[(size_t)m * DD + n] = acc[mi][ni][r] + bias[n];
      }
}

// ---------------------------------------------------------------------------
// Flash attention (unchanged).
// ---------------------------------------------------------------------------
__launch_bounds__(256, 4)
__global__ void attn_fwd(const bf16* __restrict__ Q, const bf16* __restrict__ Kg,
                         const bf16* __restrict__ Vt, bf16* __restrict__ ctx) {
  __shared__ __align__(16) bf16 kbuf[2][4096];
  __shared__ __align__(16) bf16 vbuf[2][4096];
  __shared__ __align__(16) bf16 pbuf[4][1024];
  const int tid  = threadIdx.x;
  const int lane = tid & 63, wv = tid >> 6;
  const int quad = lane >> 4, l15 = lane & 15;
  const int bx = blockIdx.x;
  const int sl = bx >> 3;
  const int c  = 31 - (sl >> 2);
  const int bh = (bx & 7) + 8 * (sl & 3);
  const int qr = c * 64 + wv * 16;
  const int ntiles = c + 1;

  const bf16* Kbh = Kg + (size_t)bh * TT * HD;
  const bf16* Vbh = Vt + (size_t)bh * HD * TT;

  const int k0s = tid >> 3,  c0s = (tid & 7) ^ (k0s & 7);
  const int s1  = 256 + tid;
  const int k1s = s1 >> 3,   c1s = (s1 & 7) ^ (k1s & 7);

  int foff[4][2];
  for (int sub = 0; sub < 4; sub++)
    for (int h = 0; h < 2; h++)
      foff[sub][h] = (((sub * 16 + l15) * 8) + ((h * 4 + quad) ^ (l15 & 7))) * 8;

  const bf16* qp = Q + ((size_t)bh * TT + qr + l15) * HD + quad * 8;
  bf16x8 aq0 = *(const bf16x8*)qp;
  bf16x8 aq1 = *(const bf16x8*)(qp + 32);

  float lrow = 0.f;
  f32x4 acc[4] = {};
  bf16* pb = pbuf[wv];
  const int pswz = l15 & 7;

  gl_lds16(Kbh + (size_t)k0s * HD + c0s * 8, (char*)kbuf[0] + wv * 1024);
  gl_lds16(Kbh + (size_t)k1s * HD + c1s * 8, (char*)kbuf[0] + 4096 + wv * 1024);
  gl_lds16(Vbh + (size_t)k0s * TT + c0s * 8, (char*)vbuf[0] + wv * 1024);
  gl_lds16(Vbh + (size_t)k1s * TT + c1s * 8, (char*)vbuf[0] + 4096 + wv * 1024);

  for (int t = 0; t < ntiles; t++) {
    const int kt = t * 64;
    __syncthreads();
    if (t + 1 < ntiles) {
      bf16* kn = kbuf[(t + 1) & 1];
      bf16* vn = vbuf[(t + 1) & 1];
      gl_lds16(Kbh + (size_t)(kt + 64 + k0s) * HD + c0s * 8, (char*)kn + wv * 1024);
      gl_lds16(Kbh + (size_t)(kt + 64 + k1s) * HD + c1s * 8, (char*)kn + 4096 + wv * 1024);
      gl_lds16(Vbh + (size_t)k0s * TT + kt + 64 + c0s * 8, (char*)vn + wv * 1024);
      gl_lds16(Vbh + (size_t)k1s * TT + kt + 64 + c1s * 8, (char*)vn + 4096 + wv * 1024);
    }
    const bf16* kc = kbuf[t & 1];
    const bf16* vc = vbuf[t & 1];
    const bool last = (t == ntiles - 1);

    float p[4][4];
    for (int sub = 0; sub < 4; sub++) {
      if (last && kt + sub * 16 > qr + 15) {
        p[sub][0] = p[sub][1] = p[sub][2] = p[sub][3] = 0.f;
        continue;
      }
      bf16x8 ak0 = *(const bf16x8*)(kc + foff[sub][0]);
      bf16x8 ak1 = *(const bf16x8*)(kc + foff[sub][1]);
      f32x4 z = {};
      f32x4 st = mfma16(ak0, aq0, z);
      st = mfma16(ak1, aq1, st);
      if (last) {
        for (int r = 0; r < 4; r++) {
          int k_abs = kt + sub * 16 + quad * 4 + r;
          p[sub][r] = (k_abs > qr + l15) ? 0.f
                      : __builtin_amdgcn_exp2f(st[r] - M0);
        }
      } else {
        for (int r = 0; r < 4; r++)
          p[sub][r] = __builtin_amdgcn_exp2f(st[r] - M0);
      }
      lrow += (p[sub][0] + p[sub][1]) + (p[sub][2] + p[sub][3]);
    }

    for (int sub = 0; sub < 4; sub++) {
      bf16x4 pk = { (bf16)p[sub][0], (bf16)p[sub][1], (bf16)p[sub][2], (bf16)p[sub][3] };
      int cch = sub * 2 + (quad >> 1);
      *(bf16x4*)&pb[l15 * 64 + ((cch ^ pswz) * 8 + (quad & 1) * 4)] = pk;
    }
    bf16x8 ap0 = *(const bf16x8*)&pb[l15 * 64 + ((quad ^ pswz) * 8)];
    bf16x8 ap1 = *(const bf16x8*)&pb[l15 * 64 + (((4 + quad) ^ pswz) * 8)];

    for (int ni = 0; ni < 4; ni++) {
      bf16x8 v0 = *(const bf16x8*)(vc + foff[ni][0]);
      bf16x8 v1 = *(const bf16x8*)(vc + foff[ni][1]);
      acc[ni] = mfma16(ap0, v0, acc[ni]);
      acc[ni] = mfma16(ap1, v1, acc[ni]);
    }
  }

  lrow += __shfl_xor(lrow, 16, 64);
  lrow += __shfl_xor(lrow, 32, 64);
  float invl = 1.f / lrow;
  float invq[4];
  for (int r = 0; r < 4; r++)
    invq[r] = __shfl(invl, (lane & 48) | (quad * 4 + r), 64);
  int b = bh >> 4, h = bh & (HH - 1);
  for (int ni = 0; ni < 4; ni++)
    for (int r = 0; r < 4; r++) {
      int tq = qr + quad * 4 + r;
      ctx[((size_t)(b * TT + tq)) * DD + h * HD + ni * 16 + l15] = (bf16)(acc[ni][r] * invq[r]);
    }
}

// ---------------------------------------------------------------------------
// launch
// ---------------------------------------------------------------------------
extern "C" void kernel_launch(void* const* d_in, const int* in_sizes, int n_in,
                              void* d_out, int out_size, void* d_ws, size_t ws_size,
                              hipStream_t stream) {
  const float* x  = (const float*)d_in[0];
  const float* Wq = (const float*)d_in[1];
  const float* bq = (const float*)d_in[2];
  const float* Wk = (const float*)d_in[3];
  const float* bk = (const float*)d_in[4];
  const float* Wv = (const float*)d_in[5];
  const float* bv = (const float*)d_in[6];
  const float* Wo = (const float*)d_in[7];
  const float* bo = (const float*)d_in[8];
  float* out = (float*)d_out;
  float* outK = out + (size_t)MM * DD;
  float* outV = out + (size_t)2 * MM * DD;

  char* ws = (char*)d_ws;
  bf16* xb   = (bf16*)(ws);
  bf16* wqb  = (bf16*)(ws + (8  << 20));
  bf16* wkb  = (bf16*)(ws + (10 << 20));
  bf16* wvb  = (bf16*)(ws + (12 << 20));
  bf16* wob  = (bf16*)(ws + (14 << 20));
  bf16* qbuf = (bf16*)(ws + (16 << 20));
  bf16* kbuf = (bf16*)(ws + (24 << 20));
  bf16* vtb  = (bf16*)(ws + (32 << 20));
  bf16* ctxb = (bf16*)(ws + (40 << 20));

  cvt_all<<<(2 << 20) / 256, 256, 0, stream>>>(x, Wq, Wk, Wv, Wo,
                                               xb, wqb, wkb, wvb, wob);

  gemm_qkv<<<512, 512, 0, stream>>>(xb, wqb, wkb, wvb, bq, bk, bv,
                                    qbuf, kbuf, vtb, outK, outV);

  attn_fwd<<<1024, 256, 0, stream>>>(qbuf, kbuf, vtb, ctxb);

  gemm_o<<<dim3(MM / 64, DD / 128), 256, 0, stream>>>(ctxb, wob, bo, out);
}

// Round 3
// 182.202 us; speedup vs baseline: 1.1230x; 1.1230x over previous
//
#include <hip/hip_runtime.h>

#define BB 2
#define TT 2048
#define DD 1024
#define HH 16
#define HD 64
#define MM (BB*TT)

typedef __bf16 bf16;
typedef __bf16 bf16x4 __attribute__((ext_vector_type(4)));
typedef __bf16 bf16x8 __attribute__((ext_vector_type(8)));
typedef float  f32x4  __attribute__((ext_vector_type(4)));

#define QSCALE 0.1803368801111244f   // 0.125 * log2(e)
#define M0 16.0f                     // fixed softmax shift (exp2 domain)

__device__ __forceinline__ void gl_lds16(const void* g, void* l) {
  __builtin_amdgcn_global_load_lds(
      (const __attribute__((address_space(1))) void*)g,
      (__attribute__((address_space(3))) void*)l, 16, 0, 0);
}
__device__ __forceinline__ f32x4 mfma16(bf16x8 a, bf16x8 b, f32x4 c) {
  return __builtin_amdgcn_mfma_f32_16x16x32_bf16(a, b, c, 0, 0, 0);
}

// ---------------------------------------------------------------------------
// single fused convert: x (4M elems) + 4 weights (1M each) fp32 -> bf16
// ---------------------------------------------------------------------------
__global__ void cvt_all(const float* __restrict__ x,
                        const float* __restrict__ w0, const float* __restrict__ w1,
                        const float* __restrict__ w2, const float* __restrict__ w3,
                        bf16* __restrict__ xd,
                        bf16* __restrict__ d0, bf16* __restrict__ d1,
                        bf16* __restrict__ d2, bf16* __restrict__ d3) {
  int i = blockIdx.x * blockDim.x + threadIdx.x;   // 2M float4 slots
  const float* s;
  bf16* d;
  int off;
  if (i < (1 << 20)) { s = x; d = xd; off = i; }
  else {
    int j = (i - (1 << 20)) >> 18;
    off = (i - (1 << 20)) & ((1 << 18) - 1);
    s = (j == 0) ? w0 : (j == 1) ? w1 : (j == 2) ? w2 : w3;
    d = (j == 0) ? d0 : (j == 1) ? d1 : (j == 2) ? d2 : d3;
  }
  float4 v = ((const float4*)s)[off];
  bf16x4 o = { (bf16)v.x, (bf16)v.y, (bf16)v.z, (bf16)v.w };
  ((bf16x4*)d)[off] = o;
}

// ---------------------------------------------------------------------------
// Fused QKV, 512 blocks x 512 threads (8 waves, wave grid 4x2).
// R3: exact R0 structure (BK=32, 24KB LDS, same grid/epilogues — R2's BK=64
// restructure added +56MB HBM traffic and regressed). ONLY change vs R0:
// 2-bit XOR chunk swizzle within each 64B row (pre-swizzled global source,
// linear gl_lds dest; read XORs back). R0's fragment read hit 2 bank-slots
// per 16 lanes (8-way conflict, SQ_LDS_BANK_CONFLICT=4.2M); swizzle spreads
// to 8 slots (2-way = free). LDS[r][c] = G[r][c ^ ((r>>1)&3)].
// ---------------------------------------------------------------------------
__launch_bounds__(512)
__global__ void gemm_qkv(const bf16* __restrict__ X,
                         const bf16* __restrict__ Wq, const bf16* __restrict__ Wk,
                         const bf16* __restrict__ Wv,
                         const float* __restrict__ bq, const float* __restrict__ bk,
                         const float* __restrict__ bv,
                         bf16* __restrict__ qb, bf16* __restrict__ kb,
                         bf16* __restrict__ vtb,
                         float* __restrict__ kf, float* __restrict__ vf) {
  __shared__ bf16 sA[128 * 32];      // 8 KB
  __shared__ bf16 sB[2][128 * 32];   // 16 KB
  const int tid  = threadIdx.x;
  const int wv   = tid >> 6;
  const int lane = tid & 63;
  const int quad = lane >> 4, l15 = lane & 15;
  const int wy   = wv >> 1, wx = wv & 1;      // wy 0..3, wx 0..1
  const int g    = blockIdx.x >> 4;
  const int j    = blockIdx.x & 15;
  const int row  = tid >> 2;                  // 0..127
  const int c8   = ((tid & 3) ^ ((row >> 1) & 3)) * 8;  // swizzled source chunk
  const int rsw  = (l15 >> 1) & 3;            // read-side XOR
  char* lA  = (char*)sA    + wv * 1024;
  char* lB0 = (char*)sB[0] + wv * 1024;
  char* lB1 = (char*)sB[1] + wv * 1024;

  if (j < 8) {
    const int m0 = g * 128;                   // tokens
    const int n0 = j * 128;                   // output dim
    const bf16* Ab  = X  + (size_t)(m0 + row) * DD + c8;
    const bf16* Bqb = Wq + (size_t)(n0 + row) * DD + c8;
    const bf16* Bkb = Wk + (size_t)(n0 + row) * DD + c8;
    f32x4 accq[2][4] = {}, acck[2][4] = {};
    for (int k0 = 0; k0 < DD; k0 += 32) {
      gl_lds16(Ab  + k0, lA);
      gl_lds16(Bqb + k0, lB0);
      gl_lds16(Bkb + k0, lB1);
      __syncthreads();
      bf16x8 af[2], bq_[4], bk_[4];
#pragma unroll
      for (int mi = 0; mi < 2; mi++)
        af[mi] = *(const bf16x8*)(sA + (wy * 32 + mi * 16 + l15) * 32
                                     + ((quad ^ rsw) * 8));
#pragma unroll
      for (int ni = 0; ni < 4; ni++) {
        bq_[ni] = *(const bf16x8*)(sB[0] + (wx * 64 + ni * 16 + l15) * 32
                                         + ((quad ^ rsw) * 8));
        bk_[ni] = *(const bf16x8*)(sB[1] + (wx * 64 + ni * 16 + l15) * 32
                                         + ((quad ^ rsw) * 8));
      }
#pragma unroll
      for (int mi = 0; mi < 2; mi++)
#pragma unroll
        for (int ni = 0; ni < 4; ni++) {
          accq[mi][ni] = mfma16(af[mi], bq_[ni], accq[mi][ni]);
          acck[mi][ni] = mfma16(af[mi], bk_[ni], acck[mi][ni]);
        }
      __syncthreads();
    }
    for (int mi = 0; mi < 2; mi++)
      for (int ni = 0; ni < 4; ni++)
        for (int r = 0; r < 4; r++) {
          int m = m0 + wy * 32 + mi * 16 + quad * 4 + r;
          int n = n0 + wx * 64 + ni * 16 + l15;
          int b = m >> 11, t = m & (TT - 1);
          int h = n >> 6,  d = n & (HD - 1);
          size_t idx = ((size_t)(b * HH + h) * TT + t) * HD + d;
          qb[idx] = (bf16)((accq[mi][ni][r] + bq[n]) * QSCALE);
          float vk = acck[mi][ni][r] + bk[n];
          kb[idx] = (bf16)vk;
          kf[idx] = vk;
        }
  } else {
    const int m0 = (j - 8) * 128;             // Wv rows (h*64+d)
    const int n0 = g * 128;                   // tokens
    const bf16* Ab = Wv + (size_t)(m0 + row) * DD + c8;
    const bf16* Bb = X  + (size_t)(n0 + row) * DD + c8;
    f32x4 acc[2][4] = {};
    for (int k0 = 0; k0 < DD; k0 += 32) {
      gl_lds16(Ab + k0, lA);
      gl_lds16(Bb + k0, lB0);
      __syncthreads();
      bf16x8 af[2], bx_[4];
#pragma unroll
      for (int mi = 0; mi < 2; mi++)
        af[mi] = *(const bf16x8*)(sA + (wy * 32 + mi * 16 + l15) * 32
                                     + ((quad ^ rsw) * 8));
#pragma unroll
      for (int ni = 0; ni < 4; ni++)
        bx_[ni] = *(const bf16x8*)(sB[0] + (wx * 64 + ni * 16 + l15) * 32
                                        + ((quad ^ rsw) * 8));
#pragma unroll
      for (int mi = 0; mi < 2; mi++)
#pragma unroll
        for (int ni = 0; ni < 4; ni++)
          acc[mi][ni] = mfma16(af[mi], bx_[ni], acc[mi][ni]);
      __syncthreads();
    }
    for (int mi = 0; mi < 2; mi++) {
      int mbase = m0 + wy * 32 + mi * 16 + quad * 4;
      float brv[4];
      for (int r = 0; r < 4; r++) brv[r] = bv[mbase + r];
      int h = mbase >> 6, dbase = mbase & (HD - 1);
      for (int ni = 0; ni < 4; ni++) {
        int tok = n0 + wx * 64 + ni * 16 + l15;
        int b = tok >> 11, t = tok & (TT - 1);
        int bh = b * HH + h;
        float4 vv;
        float* vp = &vv.x;
        for (int r = 0; r < 4; r++) {
          float v = acc[mi][ni][r] + brv[r];
          vp[r] = v;
          vtb[((size_t)bh * HD + dbase + r) * TT + t] = (bf16)v;
        }
        *(float4*)&vf[((size_t)bh * TT + t) * HD + dbase] = vv;
      }
    }
  }
}

// ---------------------------------------------------------------------------
// gemm_o tile core (BK=64, swizzled) — unchanged.
// ---------------------------------------------------------------------------
template<int BM, int BN>
__device__ __forceinline__ void tile_core64(const bf16* __restrict__ A,
                                            const bf16* __restrict__ W,
                                            int m0, int n0,
                                            bf16* sA, bf16* sB,
                                            f32x4 (&acc)[BM/32][BN/32]) {
  const int tid  = threadIdx.x;
  const int wv   = tid >> 6;
  const int l15  = tid & 15;
  const int quad = (tid & 63) >> 4;
  const int wy   = wv >> 1, wx = wv & 1;
  const int MI_  = BM / 32, NI_ = BN / 32;
  const int srow = tid >> 3;
  const int schk = (tid & 7) ^ (srow & 7);
  const int rswz = l15 & 7;
  const bf16* Ab = A + (size_t)(m0 + srow) * DD + schk * 8;
  const bf16* Wb = W + (size_t)(n0 + srow) * DD + schk * 8;
  char* lA = (char*)sA + wv * 1024;
  char* lB = (char*)sB + wv * 1024;
  for (int k0 = 0; k0 < DD; k0 += 64) {
#pragma unroll
    for (int j = 0; j < BM / 32; j++)
      gl_lds16(Ab + (size_t)j * 32 * DD + k0, lA + j * 4096);
#pragma unroll
    for (int j = 0; j < BN / 32; j++)
      gl_lds16(Wb + (size_t)j * 32 * DD + k0, lB + j * 4096);
    __syncthreads();
#pragma unroll
    for (int h = 0; h < 2; h++) {
      bf16x8 af[MI_], bw[NI_];
#pragma unroll
      for (int mi = 0; mi < MI_; mi++)
        af[mi] = *(const bf16x8*)(sA + (wy * (BM / 2) + mi * 16 + l15) * 64
                                     + (((h * 4 + quad) ^ rswz) * 8));
#pragma unroll
      for (int ni = 0; ni < NI_; ni++)
        bw[ni] = *(const bf16x8*)(sB + (wx * (BN / 2) + ni * 16 + l15) * 64
                                     + (((h * 4 + quad) ^ rswz) * 8));
#pragma unroll
      for (int mi = 0; mi < MI_; mi++)
#pragma unroll
        for (int ni = 0; ni < NI_; ni++)
          acc[mi][ni] = mfma16(af[mi], bw[ni], acc[mi][ni]);
    }
    __syncthreads();
  }
}

__launch_bounds__(256)
__global__ void gemm_o(const bf16* __restrict__ A, const bf16* __restrict__ W,
                       const float* __restrict__ bias, float* __restrict__ out) {
  __shared__ bf16 sA[64 * 64];
  __shared__ bf16 sB[128 * 64];
  const int m0 = blockIdx.x * 64;
  const int n0 = blockIdx.y * 128;
  f32x4 acc[2][4] = {};
  tile_core64<64, 128>(A, W, m0, n0, sA, sB, acc);
  const int wv = threadIdx.x >> 6;
  const int l15 = threadIdx.x & 15, quad = (threadIdx.x & 63) >> 4;
  const int wy = wv >> 1, wx = wv & 1;
  for (int mi = 0; mi < 2; mi++)
    for (int ni = 0; ni < 4; ni++)
      for (int r = 0; r < 4; r++) {
        int m = m0 + wy * 32 + mi * 16 + quad * 4 + r;
        int n = n0 + wx * 64 + ni * 16 + l15;
        out[(size_t)m * DD + n] = acc[mi][ni][r] + bias[n];
      }
}

// ---------------------------------------------------------------------------
// Flash attention (unchanged).
// ---------------------------------------------------------------------------
__launch_bounds__(256, 4)
__global__ void attn_fwd(const bf16* __restrict__ Q, const bf16* __restrict__ Kg,
                         const bf16* __restrict__ Vt, bf16* __restrict__ ctx) {
  __shared__ __align__(16) bf16 kbuf[2][4096];
  __shared__ __align__(16) bf16 vbuf[2][4096];
  __shared__ __align__(16) bf16 pbuf[4][1024];
  const int tid  = threadIdx.x;
  const int lane = tid & 63, wv = tid >> 6;
  const int quad = lane >> 4, l15 = lane & 15;
  const int bx = blockIdx.x;
  const int sl = bx >> 3;
  const int c  = 31 - (sl >> 2);
  const int bh = (bx & 7) + 8 * (sl & 3);
  const int qr = c * 64 + wv * 16;
  const int ntiles = c + 1;

  const bf16* Kbh = Kg + (size_t)bh * TT * HD;
  const bf16* Vbh = Vt + (size_t)bh * HD * TT;

  const int k0s = tid >> 3,  c0s = (tid & 7) ^ (k0s & 7);
  const int s1  = 256 + tid;
  const int k1s = s1 >> 3,   c1s = (s1 & 7) ^ (k1s & 7);

  int foff[4][2];
  for (int sub = 0; sub < 4; sub++)
    for (int h = 0; h < 2; h++)
      foff[sub][h] = (((sub * 16 + l15) * 8) + ((h * 4 + quad) ^ (l15 & 7))) * 8;

  const bf16* qp = Q + ((size_t)bh * TT + qr + l15) * HD + quad * 8;
  bf16x8 aq0 = *(const bf16x8*)qp;
  bf16x8 aq1 = *(const bf16x8*)(qp + 32);

  float lrow = 0.f;
  f32x4 acc[4] = {};
  bf16* pb = pbuf[wv];
  const int pswz = l15 & 7;

  gl_lds16(Kbh + (size_t)k0s * HD + c0s * 8, (char*)kbuf[0] + wv * 1024);
  gl_lds16(Kbh + (size_t)k1s * HD + c1s * 8, (char*)kbuf[0] + 4096 + wv * 1024);
  gl_lds16(Vbh + (size_t)k0s * TT + c0s * 8, (char*)vbuf[0] + wv * 1024);
  gl_lds16(Vbh + (size_t)k1s * TT + c1s * 8, (char*)vbuf[0] + 4096 + wv * 1024);

  for (int t = 0; t < ntiles; t++) {
    const int kt = t * 64;
    __syncthreads();
    if (t + 1 < ntiles) {
      bf16* kn = kbuf[(t + 1) & 1];
      bf16* vn = vbuf[(t + 1) & 1];
      gl_lds16(Kbh + (size_t)(kt + 64 + k0s) * HD + c0s * 8, (char*)kn + wv * 1024);
      gl_lds16(Kbh + (size_t)(kt + 64 + k1s) * HD + c1s * 8, (char*)kn + 4096 + wv * 1024);
      gl_lds16(Vbh + (size_t)k0s * TT + kt + 64 + c0s * 8, (char*)vn + wv * 1024);
      gl_lds16(Vbh + (size_t)k1s * TT + kt + 64 + c1s * 8, (char*)vn + 4096 + wv * 1024);
    }
    const bf16* kc = kbuf[t & 1];
    const bf16* vc = vbuf[t & 1];
    const bool last = (t == ntiles - 1);

    float p[4][4];
    for (int sub = 0; sub < 4; sub++) {
      if (last && kt + sub * 16 > qr + 15) {
        p[sub][0] = p[sub][1] = p[sub][2] = p[sub][3] = 0.f;
        continue;
      }
      bf16x8 ak0 = *(const bf16x8*)(kc + foff[sub][0]);
      bf16x8 ak1 = *(const bf16x8*)(kc + foff[sub][1]);
      f32x4 z = {};
      f32x4 st = mfma16(ak0, aq0, z);
      st = mfma16(ak1, aq1, st);
      if (last) {
        for (int r = 0; r < 4; r++) {
          int k_abs = kt + sub * 16 + quad * 4 + r;
          p[sub][r] = (k_abs > qr + l15) ? 0.f
                      : __builtin_amdgcn_exp2f(st[r] - M0);
        }
      } else {
        for (int r = 0; r < 4; r++)
          p[sub][r] = __builtin_amdgcn_exp2f(st[r] - M0);
      }
      lrow += (p[sub][0] + p[sub][1]) + (p[sub][2] + p[sub][3]);
    }

    for (int sub = 0; sub < 4; sub++) {
      bf16x4 pk = { (bf16)p[sub][0], (bf16)p[sub][1], (bf16)p[sub][2], (bf16)p[sub][3] };
      int cch = sub * 2 + (quad >> 1);
      *(bf16x4*)&pb[l15 * 64 + ((cch ^ pswz) * 8 + (quad & 1) * 4)] = pk;
    }
    bf16x8 ap0 = *(const bf16x8*)&pb[l15 * 64 + ((quad ^ pswz) * 8)];
    bf16x8 ap1 = *(const bf16x8*)&pb[l15 * 64 + (((4 + quad) ^ pswz) * 8)];

    for (int ni = 0; ni < 4; ni++) {
      bf16x8 v0 = *(const bf16x8*)(vc + foff[ni][0]);
      bf16x8 v1 = *(const bf16x8*)(vc + foff[ni][1]);
      acc[ni] = mfma16(ap0, v0, acc[ni]);
      acc[ni] = mfma16(ap1, v1, acc[ni]);
    }
  }

  lrow += __shfl_xor(lrow, 16, 64);
  lrow += __shfl_xor(lrow, 32, 64);
  float invl = 1.f / lrow;
  float invq[4];
  for (int r = 0; r < 4; r++)
    invq[r] = __shfl(invl, (lane & 48) | (quad * 4 + r), 64);
  int b = bh >> 4, h = bh & (HH - 1);
  for (int ni = 0; ni < 4; ni++)
    for (int r = 0; r < 4; r++) {
      int tq = qr + quad * 4 + r;
      ctx[((size_t)(b * TT + tq)) * DD + h * HD + ni * 16 + l15] = (bf16)(acc[ni][r] * invq[r]);
    }
}

// ---------------------------------------------------------------------------
// launch
// ---------------------------------------------------------------------------
extern "C" void kernel_launch(void* const* d_in, const int* in_sizes, int n_in,
                              void* d_out, int out_size, void* d_ws, size_t ws_size,
                              hipStream_t stream) {
  const float* x  = (const float*)d_in[0];
  const float* Wq = (const float*)d_in[1];
  const float* bq = (const float*)d_in[2];
  const float* Wk = (const float*)d_in[3];
  const float* bk = (const float*)d_in[4];
  const float* Wv = (const float*)d_in[5];
  const float* bv = (const float*)d_in[6];
  const float* Wo = (const float*)d_in[7];
  const float* bo = (const float*)d_in[8];
  float* out = (float*)d_out;
  float* outK = out + (size_t)MM * DD;
  float* outV = out + (size_t)2 * MM * DD;

  char* ws = (char*)d_ws;
  bf16* xb   = (bf16*)(ws);
  bf16* wqb  = (bf16*)(ws + (8  << 20));
  bf16* wkb  = (bf16*)(ws + (10 << 20));
  bf16* wvb  = (bf16*)(ws + (12 << 20));
  bf16* wob  = (bf16*)(ws + (14 << 20));
  bf16* qbuf = (bf16*)(ws + (16 << 20));
  bf16* kbuf = (bf16*)(ws + (24 << 20));
  bf16* vtb  = (bf16*)(ws + (32 << 20));
  bf16* ctxb = (bf16*)(ws + (40 << 20));

  cvt_all<<<(2 << 20) / 256, 256, 0, stream>>>(x, Wq, Wk, Wv, Wo,
                                               xb, wqb, wkb, wvb, wob);

  gemm_qkv<<<512, 512, 0, stream>>>(xb, wqb, wkb, wvb, bq, bk, bv,
                                    qbuf, kbuf, vtb, outK, outV);

  attn_fwd<<<1024, 256, 0, stream>>>(qbuf, kbuf, vtb, ctxb);

  gemm_o<<<dim3(MM / 64, DD / 128), 256, 0, stream>>>(ctxb, wob, bo, out);
}